// Round 11
// baseline (138.719 us; speedup 1.0000x reference)
//
#include <hip/hip_runtime.h>
#include <hip/hip_bf16.h>
#include <math.h>

typedef __bf16 bf16;
typedef __bf16 bf16x8 __attribute__((ext_vector_type(8)));
typedef __bf16 bf16x4 __attribute__((ext_vector_type(4)));
typedef float f32x2 __attribute__((ext_vector_type(2)));
typedef float f32x4 __attribute__((ext_vector_type(4)));
typedef float f32x16 __attribute__((ext_vector_type(16)));

#define DEV __device__ __forceinline__
#define AS1(p) ((const __attribute__((address_space(1))) void*)(p))
#define AS3(p) ((__attribute__((address_space(3))) void*)(p))

// ---------------- problem sizes ----------------
#define Bsz 2
#define Lseq 2048
#define Dm 1024
#define Hh 16
#define HD 64
#define BL (Bsz * Lseq)   // 4096 rows
#define TN (3 * Dm)       // 3072

#define LOG2E 1.44269504088896f

// ---------------- workspace layout (bytes) ----------------
#define OFF_XATT  ((size_t)0)                            // xbf bf16 8.39MB; att aliases after gemm1
#define OFF_WQKVT (OFF_XATT  + (size_t)BL * Dm * 2)      // 6.29MB
#define OFF_WOUTT (OFF_WQKVT + (size_t)TN * Dm * 2)      // 2.10MB
#define OFF_TAB   (OFF_WOUTT + (size_t)Dm * Dm * 2)      // 0.52MB
#define OFF_Q     (OFF_TAB   + (size_t)Lseq * 32 * 8)    // 8.39MB q bf16 [32][2048][64]
#define OFF_K     (OFF_Q     + (size_t)BL * Dm * 2)      // 8.39MB
#define OFF_VT    (OFF_K     + (size_t)BL * Dm * 2)      // 8.39MB vT bf16 [32][64][2048]
// end = 42.5 MB

DEV float exp2_fast(float x) {   // 2^x, single v_exp_f32
    float r;
    asm("v_exp_f32 %0, %1" : "=v"(r) : "v"(x));
    return r;
}
// v_permlane32_swap_b32 a,b: a = {a.lo, b.lo}, b = {a.hi, b.hi}.
// ONLY safe when a and b hold DISTINCT live values (R9 post-mortem:
// identical-valued operands get register-coalesced -> self-swap garbage).
DEV void plswap(unsigned& a, unsigned& b) {
    asm("v_permlane32_swap_b32 %0, %1" : "+v"(a), "+v"(b));
}
DEV float max3f(float a, float b, float c) {
    float r;
    asm("v_max3_f32 %0, %1, %2, %3" : "=v"(r) : "v"(a), "v"(b), "v"(c));
    return r;
}
DEV f32x2 pkadd2(f32x2 a, f32x2 b) {   // v_pk_add_f32: 2 adds / instruction
    f32x2 r;
    asm("v_pk_add_f32 %0, %1, %2" : "=v"(r) : "v"(a), "v"(b));
    return r;
}
DEV f32x2 mk2(float a, float b) { f32x2 r; r[0] = a; r[1] = b; return r; }

// ---------------- fused prep: convert + 2 transposes + sincos table --------
// R11: one kernel, 4 block-ranges (was 4 dispatches; saves launch gaps and
// runs the independent prep stages concurrently across CUs).
#define NB_CONV 2048              // (BL*Dm/8)/256
#define NB_TQ   3072              // (TN/32)*(Dm/32)
#define NB_TO   1024              // (Dm/32)*(Dm/32)
#define NB_SC   256               // Lseq*32/256
__global__ __launch_bounds__(256) void k_prep(const float* __restrict__ x,
                                              const float* __restrict__ Wqkv,
                                              const float* __restrict__ Wout,
                                              bf16* __restrict__ xbf,
                                              bf16* __restrict__ wqkvT,
                                              bf16* __restrict__ woutT,
                                              float2* __restrict__ tab) {
    const int bb = blockIdx.x;
    const int tid = threadIdx.x;
    if (bb < NB_CONV) {
        int i = bb * 256 + tid;
        const float4* in4 = (const float4*)x;
        float4 a = in4[i * 2], b = in4[i * 2 + 1];
        bf16x8 o;
        o[0] = (bf16)a.x; o[1] = (bf16)a.y; o[2] = (bf16)a.z; o[3] = (bf16)a.w;
        o[4] = (bf16)b.x; o[5] = (bf16)b.y; o[6] = (bf16)b.z; o[7] = (bf16)b.w;
        ((bf16x8*)xbf)[i] = o;
    } else if (bb < NB_CONV + NB_TQ + NB_TO) {
        const bool isQ = bb < NB_CONV + NB_TQ;
        const int lb = isQ ? bb - NB_CONV : bb - (NB_CONV + NB_TQ);
        const int nx = isQ ? (TN / 32) : (Dm / 32);
        const int C = isQ ? TN : Dm;           // R = Dm for both
        const float* in = isQ ? Wqkv : Wout;
        bf16* out = isQ ? wqkvT : woutT;
        __shared__ float t[32][33];
        const int bx = (lb % nx) * 32, by = (lb / nx) * 32;
        const int tx = tid & 31, ty = tid >> 5;
#pragma unroll
        for (int i = 0; i < 32; i += 8)
            t[ty + i][tx] = in[(size_t)(by + ty + i) * C + bx + tx];
        __syncthreads();
#pragma unroll
        for (int i = 0; i < 32; i += 8)
            out[(size_t)(bx + ty + i) * Dm + by + tx] = (bf16)t[tx][ty + i];
    } else {
        int idx = (bb - (NB_CONV + NB_TQ + NB_TO)) * 256 + tid;
        int pos = idx >> 5, tt = idx & 31;
        float theta = powf(10000.0f, -(float)tt * (1.0f / 32.0f));
        float f = (float)pos * theta;
        tab[idx] = make_float2(sinf(f), cosf(f));
    }
}

// ---------------- bf16 GEMM, 128x128 tile, BK=64 ----------------
// global_load_lds staging (rule #21 both-sides swizzle); full-unrolled
// epilogues (rule #20). 1D grid + bijective XCD-chunk swizzle (T1) --
// measured -4.4us on the GEMM pair in R8.
template <int EPI>
DEV void gemm_body(const bf16* __restrict__ A,
                   const bf16* __restrict__ BT,
                   const float* __restrict__ bias,
                   float* __restrict__ C,
                   bf16* __restrict__ qo,
                   bf16* __restrict__ ko,
                   bf16* __restrict__ vt,
                   const float2* __restrict__ tab,
                   int m0, int n0, int N, int K) {
    __shared__ uint4 smem4[2048];   // 32KB: A tile 16KB + B tile 16KB
    char* Al = (char*)smem4;
    char* Bl = (char*)smem4 + 16384;
    const int tid = threadIdx.x;
    const int w = tid >> 6, lane = tid & 63, lg = lane >> 4, lr = lane & 15;
    const int wm = (w >> 1) * 64, wn = (w & 1) * 64;
    const char* Ab = (const char*)A;
    const char* Bb = (const char*)BT;
    const size_t Kb = (size_t)K * 2;

    f32x4 acc[4][4] = {};

    const int rowL = lane >> 3;                    // 0..7 within 8-row group
    const int j16 = ((lane & 7) ^ rowL) * 16;      // pre-swizzled source chunk byte

    for (int kt = 0; kt < K; kt += 64) {
#pragma unroll
        for (int c = 0; c < 4; ++c) {
            const int R0 = (w * 4 + c) * 8;
            const int row = R0 + rowL;
            __builtin_amdgcn_global_load_lds(AS1(Ab + (size_t)(m0 + row) * Kb + kt * 2 + j16),
                                             AS3(Al + R0 * 128), 16, 0, 0);
            __builtin_amdgcn_global_load_lds(AS1(Bb + (size_t)(n0 + row) * Kb + kt * 2 + j16),
                                             AS3(Bl + R0 * 128), 16, 0, 0);
        }
        __syncthreads();
#pragma unroll
        for (int kf = 0; kf < 2; ++kf) {
            bf16x8 af[4], bfr[4];
#pragma unroll
            for (int i = 0; i < 4; ++i) {
                int ra = wm + i * 16 + lr;
                af[i] = *(const bf16x8*)(Al + ra * 128 + ((kf * 64 + lg * 16) ^ ((ra & 7) << 4)));
                int rb = wn + i * 16 + lr;
                bfr[i] = *(const bf16x8*)(Bl + rb * 128 + ((kf * 64 + lg * 16) ^ ((rb & 7) << 4)));
            }
#pragma unroll
            for (int i = 0; i < 4; ++i)
#pragma unroll
                for (int j = 0; j < 4; ++j)
                    acc[i][j] = __builtin_amdgcn_mfma_f32_16x16x32_bf16(af[i], bfr[j], acc[i][j], 0, 0, 0);
        }
        __syncthreads();
    }

    if constexpr (EPI == 0) {
#pragma unroll
        for (int i = 0; i < 4; ++i) {
            int row = m0 + wm + i * 16 + lg * 4;
#pragma unroll
            for (int j = 0; j < 4; ++j) {
                int col = n0 + wn + j * 16 + lr;
                float bv = bias[col];
#pragma unroll
                for (int r = 0; r < 4; ++r)
                    C[(size_t)(row + r) * N + col] = acc[i][j][r] + bv;
            }
        }
    } else {
        const int phase = n0 >> 10;            // 0=q 1=k 2=v
        const int c0 = n0 + wn;
        const int h = (c0 & 1023) >> 6;
        const int b = m0 >> 11;
        const int bh = b * 16 + h;
        const int lbase = (m0 & 2047) + wm;
        float bv[4];
#pragma unroll
        for (int j = 0; j < 4; ++j) bv[j] = bias[c0 + j * 16 + lr];
        float* Lw = (float*)((char*)smem4 + w * 4096);

#pragma unroll   // FULL unroll: compile-time acc indices (rule #20)
        for (int i = 0; i < 4; ++i) {
#pragma unroll
            for (int j = 0; j < 4; ++j)
#pragma unroll
                for (int r = 0; r < 4; ++r)
                    Lw[(lg * 4 + r) * 64 + j * 16 + lr] = acc[i][j][r] + bv[j];
            __syncthreads();
            if (phase < 2) {
                // q gets 1/8 (scores) * log2e (exp2-domain softmax) folded in
                const float scale = (phase == 0) ? 0.125f * LOG2E : 1.0f;
                bf16* dst = (phase == 0 ? qo : ko) + (size_t)bh * Lseq * 64;
#pragma unroll
                for (int j = 0; j < 4; ++j)
#pragma unroll
                    for (int r = 0; r < 4; ++r) {
                        int rl = lg * 4 + r;
                        int d = j * 16 + lr;
                        int l = lbase + i * 16 + rl;
                        float v = Lw[rl * 64 + d];
                        int dp = (d < 32) ? (2 * d + 1) : (2 * d - 64);
                        float p = Lw[rl * 64 + dp];
                        float2 f = tab[l * 32 + (d & 31)];
                        float val = ((d < 32) ? (v - p) * f.x : (v + p) * f.y) * scale;
                        dst[(size_t)l * 64 + d] = (bf16)val;
                    }
            } else {
                int d = lane;
                int lb = lbase + i * 16;
                bf16x8 o1, o2;
#pragma unroll
                for (int rw = 0; rw < 8; ++rw) {
                    o1[rw] = (bf16)Lw[rw * 64 + d];
                    o2[rw] = (bf16)Lw[(rw + 8) * 64 + d];
                }
                bf16* dst = vt + ((size_t)bh * 64 + d) * Lseq + lb;
                *(bf16x8*)dst = o1;
                *(bf16x8*)(dst + 8) = o2;
            }
            __syncthreads();
        }
    }
}

// XCD-chunk swizzle: nwg % 8 == 0 (768 / 256), bijective.
DEV void xcd_tile(int nx, int nwg, int& m0, int& n0) {
    int id = blockIdx.x;
    int id2 = (id & 7) * (nwg >> 3) + (id >> 3);
    n0 = (id2 % nx) * 128;
    m0 = (id2 / nx) * 128;
}

__global__ __launch_bounds__(256) void k_gemm_qkv(const bf16* __restrict__ A,
                                                  const bf16* __restrict__ BT,
                                                  const float* __restrict__ bias,
                                                  bf16* __restrict__ qo,
                                                  bf16* __restrict__ ko,
                                                  bf16* __restrict__ vt,
                                                  const float2* __restrict__ tab) {
    int m0, n0;
    xcd_tile(TN / 128, (TN / 128) * (BL / 128), m0, n0);
    gemm_body<1>(A, BT, bias, nullptr, qo, ko, vt, tab, m0, n0, TN, Dm);
}
__global__ __launch_bounds__(256) void k_gemm_out(const bf16* __restrict__ A,
                                                  const bf16* __restrict__ BT,
                                                  const float* __restrict__ bias,
                                                  float* __restrict__ C) {
    int m0, n0;
    xcd_tile(Dm / 128, (Dm / 128) * (BL / 128), m0, n0);
    gemm_body<0>(A, BT, bias, C, nullptr, nullptr, nullptr, nullptr, m0, n0, Dm, Dm);
}

// ---------------- stage 3: flash attention (swapped-operand, 32x32x16) ------
// R11 = R10 body (137.5us PASS) with the softmax reductions rewritten to cut
// VALU instruction COUNT (attn is VALU-issue-bound: MFMA 24% + VALU 53% of
// issue slots): max 31->16 via v_max3_f32 tree, exp-subtract 32->16 via
// v_pk_add_f32 (-m broadcast), sum 31->16 via v_pk_add_f32 tree.
DEV f32x16 mfma32(bf16x8 a, bf16x8 b, f32x16 c) {
    return __builtin_amdgcn_mfma_f32_32x32x16_bf16(a, b, c, 0, 0, 0);
}
DEV unsigned packbf(float lo, float hi) {
    unsigned short a = __builtin_bit_cast(unsigned short, (bf16)lo);
    unsigned short b = __builtin_bit_cast(unsigned short, (bf16)hi);
    return (unsigned)a | ((unsigned)b << 16);
}

DEV void stage_k(const char* kb, char* dst, int j0, int qw, int lane) {
#pragma unroll
    for (int c = 0; c < 2; ++c) {
        const int j = qw * 2 + c;              // chunk 0..7 (wave-uniform)
        const int rsw = lane ^ j;              // pre-swizzled source row
        __builtin_amdgcn_global_load_lds(AS1(kb + (size_t)(j0 + rsw) * 128 + j * 16),
                                         AS3(dst + j * 1024), 16, 0, 0);
    }
}
DEV void stage_v(const char* vb, char* dst, int j0, int qw, int lane) {
#pragma unroll
    for (int c = 0; c < 2; ++c) {
        const int j = qw * 2 + c;
        const int rsw = lane ^ j;
        __builtin_amdgcn_global_load_lds(AS1(vb + (size_t)rsw * 4096 + (size_t)j0 * 2 + j * 16),
                                         AS3(dst + j * 1024), 16, 0, 0);
    }
}

__global__ __launch_bounds__(512, 4) void k_attn(const bf16* __restrict__ Q,
                                                 const bf16* __restrict__ Kt,
                                                 const bf16* __restrict__ Vt,
                                                 bf16* __restrict__ Op) {
    __shared__ uint4 smem4[4096];   // 64KB: 2 halves x (2 bufs x [K 8K | V 8K])
    char* base = (char*)smem4;
    const int tid = threadIdx.x;
    const int w = tid >> 6, lane = tid & 63;
    const int qw = w & 3, s = w >> 2;
    const int hi = lane >> 5, l31 = lane & 31;
    const int bid = blockIdx.x;
    const int bh = bid >> 4, qt = bid & 15;
    const int q0 = qt * 128 + qw * 32;
    const char* qb = (const char*)(Q + (size_t)bh * Lseq * 64);
    const char* kb = (const char*)(Kt + (size_t)bh * Lseq * 64);
    const char* vb = (const char*)(Vt + (size_t)bh * 64 * Lseq);
    char* setb = base + s * 32768;             // this half's pipeline
    const int jbase = s * 16;                  // this half's first tile index

    // Q frags (B-operand): elem i = Q[q0+l31][kst*16 + hi*8 + i]
    bf16x8 qf[4];
#pragma unroll
    for (int kst = 0; kst < 4; ++kst)
        qf[kst] = *(const bf16x8*)(qb + (size_t)(q0 + l31) * 128 + kst * 32 + hi * 16);

    f32x16 o0 = {}, o1 = {};
    float m = -1e30f, lsum = 0.f;

    // prologue: stage tile 0 of this half into buf 0
    stage_k(kb, setb, jbase * 64, qw, lane);
    stage_v(vb, setb + 8192, jbase * 64, qw, lane);
    __syncthreads();

    for (int t = 0; t < 16; ++t) {
        const int cur = t & 1;
        const char* Kl = setb + cur * 16384;
        const char* Vl = Kl + 8192;
        char* Kn = setb + (cur ^ 1) * 16384;
        char* Vn = Kn + 8192;

        // async-stage next tile (drains at this iteration's end barrier)
        if (t < 15) {
            stage_k(kb, Kn, (jbase + t + 1) * 64, qw, lane);
            stage_v(vb, Vn, (jbase + t + 1) * 64, qw, lane);
        }

        // S^T = K * Q^T : s0 = j rows 0..31, s1 = 32..63 (col q = l31)
        f32x16 s0 = {}, s1 = {};
        __builtin_amdgcn_s_setprio(1);
#pragma unroll
        for (int kst = 0; kst < 4; ++kst) {
            const int jK = kst * 2 + hi;
            const int x = l31 ^ jK;            // jK<8: flips low 3 bits only
            bf16x8 ka = *(const bf16x8*)(Kl + jK * 1024 + x * 16);
            bf16x8 kc = *(const bf16x8*)(Kl + jK * 1024 + (32 + x) * 16);
            s0 = mfma32(ka, qf[kst], s0);
            s1 = mfma32(kc, qf[kst], s1);
        }
        __builtin_amdgcn_s_setprio(0);

        // row-max: v_max3_f32 tree (16 inst vs 31 serial fmax)
        float pm;
        {
            float a0 = max3f(s0[0], s0[1], s0[2]);
            float a1 = max3f(s0[3], s0[4], s0[5]);
            float a2 = max3f(s0[6], s0[7], s0[8]);
            float a3 = max3f(s0[9], s0[10], s0[11]);
            float a4 = max3f(s0[12], s0[13], s0[14]);
            float a5 = max3f(s0[15], s1[0], s1[1]);
            float a6 = max3f(s1[2], s1[3], s1[4]);
            float a7 = max3f(s1[5], s1[6], s1[7]);
            float a8 = max3f(s1[8], s1[9], s1[10]);
            float a9 = max3f(s1[11], s1[12], s1[13]);
            float b0 = max3f(a0, a1, s1[14]);
            float b1 = max3f(a2, a3, s1[15]);
            float b2 = max3f(a4, a5, a6);
            float b3 = max3f(a7, a8, a9);
            pm = fmaxf(max3f(b0, b1, b2), b3);
        }
        pm = fmaxf(pm, __shfl_xor(pm, 32));
        if (!__all(pm <= m + 8.0f)) {          // defer-max (T13), log2 units
            float mn = fmaxf(m, pm);
            float sc = exp2_fast(m - mn);
#pragma unroll
            for (int r = 0; r < 16; ++r) { o0[r] *= sc; o1[r] *= sc; }
            lsum *= sc; m = mn;
        }
        // exp2(s - m): packed subtract (v_pk_add_f32 with -m) + v_exp
        {
            f32x2 nm = mk2(-m, -m);
#pragma unroll
            for (int i2 = 0; i2 < 8; ++i2) {
                f32x2 pa = pkadd2(mk2(s0[2 * i2], s0[2 * i2 + 1]), nm);
                f32x2 pb = pkadd2(mk2(s1[2 * i2], s1[2 * i2 + 1]), nm);
                s0[2 * i2] = exp2_fast(pa[0]); s0[2 * i2 + 1] = exp2_fast(pa[1]);
                s1[2 * i2] = exp2_fast(pb[0]); s1[2 * i2 + 1] = exp2_fast(pb[1]);
            }
        }
        // row-sum: v_pk_add_f32 tree (16 inst vs 31 serial adds)
        float rs;
        {
            f32x2 c0 = pkadd2(mk2(s0[0], s0[1]), mk2(s0[2], s0[3]));
            f32x2 c1 = pkadd2(mk2(s0[4], s0[5]), mk2(s0[6], s0[7]));
            f32x2 c2 = pkadd2(mk2(s0[8], s0[9]), mk2(s0[10], s0[11]));
            f32x2 c3 = pkadd2(mk2(s0[12], s0[13]), mk2(s0[14], s0[15]));
            f32x2 c4 = pkadd2(mk2(s1[0], s1[1]), mk2(s1[2], s1[3]));
            f32x2 c5 = pkadd2(mk2(s1[4], s1[5]), mk2(s1[6], s1[7]));
            f32x2 c6 = pkadd2(mk2(s1[8], s1[9]), mk2(s1[10], s1[11]));
            f32x2 c7 = pkadd2(mk2(s1[12], s1[13]), mk2(s1[14], s1[15]));
            c0 = pkadd2(c0, c4); c1 = pkadd2(c1, c5);
            c2 = pkadd2(c2, c6); c3 = pkadd2(c3, c7);
            c0 = pkadd2(c0, c2); c1 = pkadd2(c1, c3);
            c0 = pkadd2(c0, c1);
            rs = c0[0] + c0[1];
        }
        rs += __shfl_xor(rs, 32);
        lsum += rs;

        // pack P to bf16 pairs; cross-half exchange = 8 in-place permlane
        // swaps on DISTINCT-valued register pairs (safe; see plswap note)
        unsigned u[16];
#pragma unroll
        for (int t2 = 0; t2 < 8; ++t2) {
            u[t2]     = packbf(s0[2 * t2], s0[2 * t2 + 1]);
            u[8 + t2] = packbf(s1[2 * t2], s1[2 * t2 + 1]);
        }
        bf16x8 pf[2][2];
#pragma unroll
        for (int J = 0; J < 2; ++J)
#pragma unroll
            for (int st = 0; st < 2; ++st) {
                const int t0 = J * 8 + st * 4;
                plswap(u[t0 + 0], u[t0 + 2]);
                plswap(u[t0 + 1], u[t0 + 3]);
                union { unsigned wd[4]; bf16x8 v; } f;
                f.wd[0] = u[t0 + 0];
                f.wd[1] = u[t0 + 1];
                f.wd[2] = u[t0 + 2];
                f.wd[3] = u[t0 + 3];
                pf[J][st] = f.v;
            }

        // O^T += V^T * P^T : o0 = d rows 0..31, o1 = 32..63 (col q = l31)
        __builtin_amdgcn_s_setprio(1);
#pragma unroll
        for (int J = 0; J < 2; ++J)
#pragma unroll
            for (int st = 0; st < 2; ++st) {
                const int jV = J * 4 + st * 2 + hi;
                const int x = l31 ^ jV;
                bf16x8 v0 = *(const bf16x8*)(Vl + jV * 1024 + x * 16);
                bf16x8 v1 = *(const bf16x8*)(Vl + jV * 1024 + (32 + x) * 16);
                o0 = mfma32(v0, pf[J][st], o0);
                o1 = mfma32(v1, pf[J][st], o1);
            }
        __builtin_amdgcn_s_setprio(0);
        __syncthreads();
    }

    // ---- combine the two KV halves (LDS exchange; K/V buffers now dead) ----
    float* ex = (float*)base;                   // per qw-wave region: 2176 floats
    if (s == 1) {
        float* r = ex + qw * 2176;
#pragma unroll
        for (int t = 0; t < 16; ++t) {
            r[t * 64 + lane] = o0[t];
            r[1024 + t * 64 + lane] = o1[t];
        }
        r[2048 + lane] = m;
        r[2112 + lane] = lsum;
    }
    __syncthreads();
    if (s == 0) {
        float* r = ex + qw * 2176;
        const float mb = r[2048 + lane], lb = r[2112 + lane];
        const float M = fmaxf(m, mb);
        const float wa = exp2_fast(m - M), wb = exp2_fast(mb - M);
        const float inv = 1.0f / (wa * lsum + wb * lb);
        const float fa = wa * inv, fb = wb * inv;
        const int b = bh >> 4, h = bh & 15;
        bf16* dst = Op + (size_t)(b * Lseq + q0 + l31) * Dm + h * 64;
        // epilogue layout: lane owns col q = l31; rows d = (r&3)+8*(r>>2)+4*hi
#pragma unroll
        for (int t = 0; t < 4; ++t) {
            bf16x4 p0, p1;
#pragma unroll
            for (int i = 0; i < 4; ++i) {
                p0[i] = (bf16)(o0[4 * t + i] * fa + r[(4 * t + i) * 64 + lane] * fb);
                p1[i] = (bf16)(o1[4 * t + i] * fa + r[1024 + (4 * t + i) * 64 + lane] * fb);
            }
            *(bf16x4*)(dst + 8 * t + 4 * hi) = p0;
            *(bf16x4*)(dst + 32 + 8 * t + 4 * hi) = p1;
        }
    }
}

// ---------------- launch ----------------
extern "C" void kernel_launch(void* const* d_in, const int* in_sizes, int n_in,
                              void* d_out, int out_size, void* d_ws, size_t ws_size,
                              hipStream_t stream) {
    (void)in_sizes; (void)n_in; (void)out_size; (void)ws_size;
    const float* x    = (const float*)d_in[0];
    const float* Wqkv = (const float*)d_in[1];
    const float* bqkv = (const float*)d_in[2];
    const float* Wout = (const float*)d_in[3];
    const float* bout = (const float*)d_in[4];
    float* out = (float*)d_out;
    char* ws = (char*)d_ws;

    bf16* xbf    = (bf16*)(ws + OFF_XATT);
    bf16* att    = (bf16*)(ws + OFF_XATT);   // aliases xbf (dead after gemm_qkv)
    bf16* wqkvT  = (bf16*)(ws + OFF_WQKVT);
    bf16* woutT  = (bf16*)(ws + OFF_WOUTT);
    float2* tab  = (float2*)(ws + OFF_TAB);
    bf16* qb     = (bf16*)(ws + OFF_Q);
    bf16* kb     = (bf16*)(ws + OFF_K);
    bf16* vt     = (bf16*)(ws + OFF_VT);

    hipLaunchKernelGGL(k_prep, dim3(NB_CONV + NB_TQ + NB_TO + NB_SC), dim3(256), 0, stream,
                       x, Wqkv, Wout, xbf, wqkvT, woutT, tab);
    hipLaunchKernelGGL(k_gemm_qkv, dim3((TN / 128) * (BL / 128)), dim3(256), 0, stream,
                       xbf, wqkvT, bqkv, qb, kb, vt, tab);
    hipLaunchKernelGGL(k_attn, dim3(32 * 16), dim3(512), 0, stream, qb, kb, vt, att);
    hipLaunchKernelGGL(k_gemm_out, dim3((Dm / 128) * (BL / 128)), dim3(256), 0, stream,
                       att, woutT, bout, out);
}

// Round 12
// 131.301 us; speedup vs baseline: 1.0565x; 1.0565x over previous
//
#include <hip/hip_runtime.h>
#include <hip/hip_bf16.h>
#include <math.h>

typedef __bf16 bf16;
typedef __bf16 bf16x8 __attribute__((ext_vector_type(8)));
typedef __bf16 bf16x4 __attribute__((ext_vector_type(4)));
typedef float f32x4 __attribute__((ext_vector_type(4)));
typedef float f32x16 __attribute__((ext_vector_type(16)));

#define DEV __device__ __forceinline__
#define AS1(p) ((const __attribute__((address_space(1))) void*)(p))
#define AS3(p) ((__attribute__((address_space(3))) void*)(p))

// ---------------- problem sizes ----------------
#define Bsz 2
#define Lseq 2048
#define Dm 1024
#define Hh 16
#define HD 64
#define BL (Bsz * Lseq)   // 4096 rows
#define TN (3 * Dm)       // 3072

#define LOG2E 1.44269504088896f

// ---------------- workspace layout (bytes) ----------------
#define OFF_XATT  ((size_t)0)                            // xbf bf16 8.39MB; att aliases after gemm1
#define OFF_WQKVT (OFF_XATT  + (size_t)BL * Dm * 2)      // 6.29MB
#define OFF_WOUTT (OFF_WQKVT + (size_t)TN * Dm * 2)      // 2.10MB
#define OFF_TAB   (OFF_WOUTT + (size_t)Dm * Dm * 2)      // 0.52MB
#define OFF_Q     (OFF_TAB   + (size_t)Lseq * 32 * 8)    // 8.39MB q bf16 [32][2048][64]
#define OFF_K     (OFF_Q     + (size_t)BL * Dm * 2)      // 8.39MB
#define OFF_VT    (OFF_K     + (size_t)BL * Dm * 2)      // 8.39MB vT bf16 [32][64][2048]
// end = 42.5 MB

DEV float exp2_fast(float x) {   // 2^x, single v_exp_f32
    float r;
    asm("v_exp_f32 %0, %1" : "=v"(r) : "v"(x));
    return r;
}
// v_permlane32_swap_b32 a,b: a = {a.lo, b.lo}, b = {a.hi, b.hi}.
// ONLY safe when a and b hold DISTINCT live values (R9 post-mortem:
// identical-valued operands get register-coalesced -> self-swap garbage).
// R11 post-mortem: do NOT hand-write v_pk_add_f32/v_max3_f32 trees here --
// pk ops need even-aligned register PAIRS; marshalling scattered scalars
// into pairs cost ~40 v_movs and regressed attn 57.9->67.9us.
DEV void plswap(unsigned& a, unsigned& b) {
    asm("v_permlane32_swap_b32 %0, %1" : "+v"(a), "+v"(b));
}

// ---------------- fused prep: convert + 2 transposes + sincos table --------
// R11 win (-8.8us): one kernel, 4 block-ranges, stages run concurrently.
#define NB_CONV 2048              // (BL*Dm/8)/256
#define NB_TQ   3072              // (TN/32)*(Dm/32)
#define NB_TO   1024              // (Dm/32)*(Dm/32)
#define NB_SC   256               // Lseq*32/256
__global__ __launch_bounds__(256) void k_prep(const float* __restrict__ x,
                                              const float* __restrict__ Wqkv,
                                              const float* __restrict__ Wout,
                                              bf16* __restrict__ xbf,
                                              bf16* __restrict__ wqkvT,
                                              bf16* __restrict__ woutT,
                                              float2* __restrict__ tab) {
    const int bb = blockIdx.x;
    const int tid = threadIdx.x;
    if (bb < NB_CONV) {
        int i = bb * 256 + tid;
        const float4* in4 = (const float4*)x;
        float4 a = in4[i * 2], b = in4[i * 2 + 1];
        bf16x8 o;
        o[0] = (bf16)a.x; o[1] = (bf16)a.y; o[2] = (bf16)a.z; o[3] = (bf16)a.w;
        o[4] = (bf16)b.x; o[5] = (bf16)b.y; o[6] = (bf16)b.z; o[7] = (bf16)b.w;
        ((bf16x8*)xbf)[i] = o;
    } else if (bb < NB_CONV + NB_TQ + NB_TO) {
        const bool isQ = bb < NB_CONV + NB_TQ;
        const int lb = isQ ? bb - NB_CONV : bb - (NB_CONV + NB_TQ);
        const int nx = isQ ? (TN / 32) : (Dm / 32);
        const int C = isQ ? TN : Dm;           // R = Dm for both
        const float* in = isQ ? Wqkv : Wout;
        bf16* out = isQ ? wqkvT : woutT;
        __shared__ float t[32][33];
        const int bx = (lb % nx) * 32, by = (lb / nx) * 32;
        const int tx = tid & 31, ty = tid >> 5;
#pragma unroll
        for (int i = 0; i < 32; i += 8)
            t[ty + i][tx] = in[(size_t)(by + ty + i) * C + bx + tx];
        __syncthreads();
#pragma unroll
        for (int i = 0; i < 32; i += 8)
            out[(size_t)(bx + ty + i) * Dm + by + tx] = (bf16)t[tx][ty + i];
    } else {
        int idx = (bb - (NB_CONV + NB_TQ + NB_TO)) * 256 + tid;
        int pos = idx >> 5, tt = idx & 31;
        float theta = powf(10000.0f, -(float)tt * (1.0f / 32.0f));
        float f = (float)pos * theta;
        tab[idx] = make_float2(sinf(f), cosf(f));
    }
}

// ---------------- bf16 GEMM, 128x128 tile, BK=64 ----------------
// global_load_lds staging (rule #21 both-sides swizzle); full-unrolled
// epilogues (rule #20). 1D grid + bijective XCD-chunk swizzle (T1) --
// measured -4.4us on the GEMM pair in R8.
template <int EPI>
DEV void gemm_body(const bf16* __restrict__ A,
                   const bf16* __restrict__ BT,
                   const float* __restrict__ bias,
                   float* __restrict__ C,
                   bf16* __restrict__ qo,
                   bf16* __restrict__ ko,
                   bf16* __restrict__ vt,
                   const float2* __restrict__ tab,
                   int m0, int n0, int N, int K) {
    __shared__ uint4 smem4[2048];   // 32KB: A tile 16KB + B tile 16KB
    char* Al = (char*)smem4;
    char* Bl = (char*)smem4 + 16384;
    const int tid = threadIdx.x;
    const int w = tid >> 6, lane = tid & 63, lg = lane >> 4, lr = lane & 15;
    const int wm = (w >> 1) * 64, wn = (w & 1) * 64;
    const char* Ab = (const char*)A;
    const char* Bb = (const char*)BT;
    const size_t Kb = (size_t)K * 2;

    f32x4 acc[4][4] = {};

    const int rowL = lane >> 3;                    // 0..7 within 8-row group
    const int j16 = ((lane & 7) ^ rowL) * 16;      // pre-swizzled source chunk byte

    for (int kt = 0; kt < K; kt += 64) {
#pragma unroll
        for (int c = 0; c < 4; ++c) {
            const int R0 = (w * 4 + c) * 8;
            const int row = R0 + rowL;
            __builtin_amdgcn_global_load_lds(AS1(Ab + (size_t)(m0 + row) * Kb + kt * 2 + j16),
                                             AS3(Al + R0 * 128), 16, 0, 0);
            __builtin_amdgcn_global_load_lds(AS1(Bb + (size_t)(n0 + row) * Kb + kt * 2 + j16),
                                             AS3(Bl + R0 * 128), 16, 0, 0);
        }
        __syncthreads();
#pragma unroll
        for (int kf = 0; kf < 2; ++kf) {
            bf16x8 af[4], bfr[4];
#pragma unroll
            for (int i = 0; i < 4; ++i) {
                int ra = wm + i * 16 + lr;
                af[i] = *(const bf16x8*)(Al + ra * 128 + ((kf * 64 + lg * 16) ^ ((ra & 7) << 4)));
                int rb = wn + i * 16 + lr;
                bfr[i] = *(const bf16x8*)(Bl + rb * 128 + ((kf * 64 + lg * 16) ^ ((rb & 7) << 4)));
            }
#pragma unroll
            for (int i = 0; i < 4; ++i)
#pragma unroll
                for (int j = 0; j < 4; ++j)
                    acc[i][j] = __builtin_amdgcn_mfma_f32_16x16x32_bf16(af[i], bfr[j], acc[i][j], 0, 0, 0);
        }
        __syncthreads();
    }

    if constexpr (EPI == 0) {
#pragma unroll
        for (int i = 0; i < 4; ++i) {
            int row = m0 + wm + i * 16 + lg * 4;
#pragma unroll
            for (int j = 0; j < 4; ++j) {
                int col = n0 + wn + j * 16 + lr;
                float bv = bias[col];
#pragma unroll
                for (int r = 0; r < 4; ++r)
                    C[(size_t)(row + r) * N + col] = acc[i][j][r] + bv;
            }
        }
    } else {
        const int phase = n0 >> 10;            // 0=q 1=k 2=v
        const int c0 = n0 + wn;
        const int h = (c0 & 1023) >> 6;
        const int b = m0 >> 11;
        const int bh = b * 16 + h;
        const int lbase = (m0 & 2047) + wm;
        float bv[4];
#pragma unroll
        for (int j = 0; j < 4; ++j) bv[j] = bias[c0 + j * 16 + lr];
        float* Lw = (float*)((char*)smem4 + w * 4096);

#pragma unroll   // FULL unroll: compile-time acc indices (rule #20)
        for (int i = 0; i < 4; ++i) {
#pragma unroll
            for (int j = 0; j < 4; ++j)
#pragma unroll
                for (int r = 0; r < 4; ++r)
                    Lw[(lg * 4 + r) * 64 + j * 16 + lr] = acc[i][j][r] + bv[j];
            __syncthreads();
            if (phase < 2) {
                // q gets 1/8 (scores) * log2e (exp2-domain softmax) folded in
                const float scale = (phase == 0) ? 0.125f * LOG2E : 1.0f;
                bf16* dst = (phase == 0 ? qo : ko) + (size_t)bh * Lseq * 64;
#pragma unroll
                for (int j = 0; j < 4; ++j)
#pragma unroll
                    for (int r = 0; r < 4; ++r) {
                        int rl = lg * 4 + r;
                        int d = j * 16 + lr;
                        int l = lbase + i * 16 + rl;
                        float v = Lw[rl * 64 + d];
                        int dp = (d < 32) ? (2 * d + 1) : (2 * d - 64);
                        float p = Lw[rl * 64 + dp];
                        float2 f = tab[l * 32 + (d & 31)];
                        float val = ((d < 32) ? (v - p) * f.x : (v + p) * f.y) * scale;
                        dst[(size_t)l * 64 + d] = (bf16)val;
                    }
            } else {
                int d = lane;
                int lb = lbase + i * 16;
                bf16x8 o1, o2;
#pragma unroll
                for (int rw = 0; rw < 8; ++rw) {
                    o1[rw] = (bf16)Lw[rw * 64 + d];
                    o2[rw] = (bf16)Lw[(rw + 8) * 64 + d];
                }
                bf16* dst = vt + ((size_t)bh * 64 + d) * Lseq + lb;
                *(bf16x8*)dst = o1;
                *(bf16x8*)(dst + 8) = o2;
            }
            __syncthreads();
        }
    }
}

// XCD-chunk swizzle: nwg % 8 == 0 (768 / 256), bijective.
DEV void xcd_tile(int nx, int nwg, int& m0, int& n0) {
    int id = blockIdx.x;
    int id2 = (id & 7) * (nwg >> 3) + (id >> 3);
    n0 = (id2 % nx) * 128;
    m0 = (id2 / nx) * 128;
}

__global__ __launch_bounds__(256) void k_gemm_qkv(const bf16* __restrict__ A,
                                                  const bf16* __restrict__ BT,
                                                  const float* __restrict__ bias,
                                                  bf16* __restrict__ qo,
                                                  bf16* __restrict__ ko,
                                                  bf16* __restrict__ vt,
                                                  const float2* __restrict__ tab) {
    int m0, n0;
    xcd_tile(TN / 128, (TN / 128) * (BL / 128), m0, n0);
    gemm_body<1>(A, BT, bias, nullptr, qo, ko, vt, tab, m0, n0, TN, Dm);
}
__global__ __launch_bounds__(256) void k_gemm_out(const bf16* __restrict__ A,
                                                  const bf16* __restrict__ BT,
                                                  const float* __restrict__ bias,
                                                  float* __restrict__ C) {
    int m0, n0;
    xcd_tile(Dm / 128, (Dm / 128) * (BL / 128), m0, n0);
    gemm_body<0>(A, BT, bias, C, nullptr, nullptr, nullptr, nullptr, m0, n0, Dm, Dm);
}

// ---------------- stage 3: flash attention (swapped-operand, 32x32x16) ------
// R12 = R10 attn body verbatim (57.9us known-good): serial fmax/add
// reductions (compiler schedules them fine), permlane P-exchange, defer-max,
// double-buffered K/V via global_load_lds, in-block KV-split + LSE combine.
DEV f32x16 mfma32(bf16x8 a, bf16x8 b, f32x16 c) {
    return __builtin_amdgcn_mfma_f32_32x32x16_bf16(a, b, c, 0, 0, 0);
}
DEV unsigned packbf(float lo, float hi) {
    unsigned short a = __builtin_bit_cast(unsigned short, (bf16)lo);
    unsigned short b = __builtin_bit_cast(unsigned short, (bf16)hi);
    return (unsigned)a | ((unsigned)b << 16);
}

DEV void stage_k(const char* kb, char* dst, int j0, int qw, int lane) {
#pragma unroll
    for (int c = 0; c < 2; ++c) {
        const int j = qw * 2 + c;              // chunk 0..7 (wave-uniform)
        const int rsw = lane ^ j;              // pre-swizzled source row
        __builtin_amdgcn_global_load_lds(AS1(kb + (size_t)(j0 + rsw) * 128 + j * 16),
                                         AS3(dst + j * 1024), 16, 0, 0);
    }
}
DEV void stage_v(const char* vb, char* dst, int j0, int qw, int lane) {
#pragma unroll
    for (int c = 0; c < 2; ++c) {
        const int j = qw * 2 + c;
        const int rsw = lane ^ j;
        __builtin_amdgcn_global_load_lds(AS1(vb + (size_t)rsw * 4096 + (size_t)j0 * 2 + j * 16),
                                         AS3(dst + j * 1024), 16, 0, 0);
    }
}

__global__ __launch_bounds__(512, 4) void k_attn(const bf16* __restrict__ Q,
                                                 const bf16* __restrict__ Kt,
                                                 const bf16* __restrict__ Vt,
                                                 bf16* __restrict__ Op) {
    __shared__ uint4 smem4[4096];   // 64KB: 2 halves x (2 bufs x [K 8K | V 8K])
    char* base = (char*)smem4;
    const int tid = threadIdx.x;
    const int w = tid >> 6, lane = tid & 63;
    const int qw = w & 3, s = w >> 2;
    const int hi = lane >> 5, l31 = lane & 31;
    const int bid = blockIdx.x;
    const int bh = bid >> 4, qt = bid & 15;
    const int q0 = qt * 128 + qw * 32;
    const char* qb = (const char*)(Q + (size_t)bh * Lseq * 64);
    const char* kb = (const char*)(Kt + (size_t)bh * Lseq * 64);
    const char* vb = (const char*)(Vt + (size_t)bh * 64 * Lseq);
    char* setb = base + s * 32768;             // this half's pipeline
    const int jbase = s * 16;                  // this half's first tile index

    // Q frags (B-operand): elem i = Q[q0+l31][kst*16 + hi*8 + i]
    bf16x8 qf[4];
#pragma unroll
    for (int kst = 0; kst < 4; ++kst)
        qf[kst] = *(const bf16x8*)(qb + (size_t)(q0 + l31) * 128 + kst * 32 + hi * 16);

    f32x16 o0 = {}, o1 = {};
    float m = -1e30f, lsum = 0.f;

    // prologue: stage tile 0 of this half into buf 0
    stage_k(kb, setb, jbase * 64, qw, lane);
    stage_v(vb, setb + 8192, jbase * 64, qw, lane);
    __syncthreads();

    for (int t = 0; t < 16; ++t) {
        const int cur = t & 1;
        const char* Kl = setb + cur * 16384;
        const char* Vl = Kl + 8192;
        char* Kn = setb + (cur ^ 1) * 16384;
        char* Vn = Kn + 8192;

        // async-stage next tile (drains at this iteration's end barrier)
        if (t < 15) {
            stage_k(kb, Kn, (jbase + t + 1) * 64, qw, lane);
            stage_v(vb, Vn, (jbase + t + 1) * 64, qw, lane);
        }

        // S^T = K * Q^T : s0 = j rows 0..31, s1 = 32..63 (col q = l31)
        f32x16 s0 = {}, s1 = {};
        __builtin_amdgcn_s_setprio(1);
#pragma unroll
        for (int kst = 0; kst < 4; ++kst) {
            const int jK = kst * 2 + hi;
            const int x = l31 ^ jK;            // jK<8: flips low 3 bits only
            bf16x8 ka = *(const bf16x8*)(Kl + jK * 1024 + x * 16);
            bf16x8 kc = *(const bf16x8*)(Kl + jK * 1024 + (32 + x) * 16);
            s0 = mfma32(ka, qf[kst], s0);
            s1 = mfma32(kc, qf[kst], s1);
        }
        __builtin_amdgcn_s_setprio(0);

        // lane-local online softmax (exp2 domain) for row q = l31
        float pm = fmaxf(s0[0], s0[1]);
#pragma unroll
        for (int r = 2; r < 16; ++r) pm = fmaxf(pm, s0[r]);
#pragma unroll
        for (int r = 0; r < 16; ++r) pm = fmaxf(pm, s1[r]);
        pm = fmaxf(pm, __shfl_xor(pm, 32));
        if (!__all(pm <= m + 8.0f)) {          // defer-max (T13), log2 units
            float mn = fmaxf(m, pm);
            float sc = exp2_fast(m - mn);
#pragma unroll
            for (int r = 0; r < 16; ++r) { o0[r] *= sc; o1[r] *= sc; }
            lsum *= sc; m = mn;
        }
        float rs = 0.f;
#pragma unroll
        for (int r = 0; r < 16; ++r) { s0[r] = exp2_fast(s0[r] - m); rs += s0[r]; }
#pragma unroll
        for (int r = 0; r < 16; ++r) { s1[r] = exp2_fast(s1[r] - m); rs += s1[r]; }
        rs += __shfl_xor(rs, 32);
        lsum += rs;

        // pack P to bf16 pairs; cross-half exchange = 8 in-place permlane
        // swaps on DISTINCT-valued register pairs (safe; see plswap note)
        unsigned u[16];
#pragma unroll
        for (int t2 = 0; t2 < 8; ++t2) {
            u[t2]     = packbf(s0[2 * t2], s0[2 * t2 + 1]);
            u[8 + t2] = packbf(s1[2 * t2], s1[2 * t2 + 1]);
        }
        bf16x8 pf[2][2];
#pragma unroll
        for (int J = 0; J < 2; ++J)
#pragma unroll
            for (int st = 0; st < 2; ++st) {
                const int t0 = J * 8 + st * 4;
                plswap(u[t0 + 0], u[t0 + 2]);
                plswap(u[t0 + 1], u[t0 + 3]);
                union { unsigned wd[4]; bf16x8 v; } f;
                f.wd[0] = u[t0 + 0];
                f.wd[1] = u[t0 + 1];
                f.wd[2] = u[t0 + 2];
                f.wd[3] = u[t0 + 3];
                pf[J][st] = f.v;
            }

        // O^T += V^T * P^T : o0 = d rows 0..31, o1 = 32..63 (col q = l31)
        __builtin_amdgcn_s_setprio(1);
#pragma unroll
        for (int J = 0; J < 2; ++J)
#pragma unroll
            for (int st = 0; st < 2; ++st) {
                const int jV = J * 4 + st * 2 + hi;
                const int x = l31 ^ jV;
                bf16x8 v0 = *(const bf16x8*)(Vl + jV * 1024 + x * 16);
                bf16x8 v1 = *(const bf16x8*)(Vl + jV * 1024 + (32 + x) * 16);
                o0 = mfma32(v0, pf[J][st], o0);
                o1 = mfma32(v1, pf[J][st], o1);
            }
        __builtin_amdgcn_s_setprio(0);
        __syncthreads();
    }

    // ---- combine the two KV halves (LDS exchange; K/V buffers now dead) ----
    float* ex = (float*)base;                   // per qw-wave region: 2176 floats
    if (s == 1) {
        float* r = ex + qw * 2176;
#pragma unroll
        for (int t = 0; t < 16; ++t) {
            r[t * 64 + lane] = o0[t];
            r[1024 + t * 64 + lane] = o1[t];
        }
        r[2048 + lane] = m;
        r[2112 + lane] = lsum;
    }
    __syncthreads();
    if (s == 0) {
        float* r = ex + qw * 2176;
        const float mb = r[2048 + lane], lb = r[2112 + lane];
        const float M = fmaxf(m, mb);
        const float wa = exp2_fast(m - M), wb = exp2_fast(mb - M);
        const float inv = 1.0f / (wa * lsum + wb * lb);
        const float fa = wa * inv, fb = wb * inv;
        const int b = bh >> 4, h = bh & 15;
        bf16* dst = Op + (size_t)(b * Lseq + q0 + l31) * Dm + h * 64;
        // epilogue layout: lane owns col q = l31; rows d = (r&3)+8*(r>>2)+4*hi
#pragma unroll
        for (int t = 0; t < 4; ++t) {
            bf16x4 p0, p1;
#pragma unroll
            for (int i = 0; i < 4; ++i) {
                p0[i] = (bf16)(o0[4 * t + i] * fa + r[(4 * t + i) * 64 + lane] * fb);
                p1[i] = (bf16)(o1[4 * t + i] * fa + r[1024 + (4 * t + i) * 64 + lane] * fb);
            }
            *(bf16x4*)(dst + 8 * t + 4 * hi) = p0;
            *(bf16x4*)(dst + 32 + 8 * t + 4 * hi) = p1;
        }
    }
}

// ---------------- launch ----------------
extern "C" void kernel_launch(void* const* d_in, const int* in_sizes, int n_in,
                              void* d_out, int out_size, void* d_ws, size_t ws_size,
                              hipStream_t stream) {
    (void)in_sizes; (void)n_in; (void)out_size; (void)ws_size;
    const float* x    = (const float*)d_in[0];
    const float* Wqkv = (const float*)d_in[1];
    const float* bqkv = (const float*)d_in[2];
    const float* Wout = (const float*)d_in[3];
    const float* bout = (const float*)d_in[4];
    float* out = (float*)d_out;
    char* ws = (char*)d_ws;

    bf16* xbf    = (bf16*)(ws + OFF_XATT);
    bf16* att    = (bf16*)(ws + OFF_XATT);   // aliases xbf (dead after gemm_qkv)
    bf16* wqkvT  = (bf16*)(ws + OFF_WQKVT);
    bf16* woutT  = (bf16*)(ws + OFF_WOUTT);
    float2* tab  = (float2*)(ws + OFF_TAB);
    bf16* qb     = (bf16*)(ws + OFF_Q);
    bf16* kb     = (bf16*)(ws + OFF_K);
    bf16* vt     = (bf16*)(ws + OFF_VT);

    hipLaunchKernelGGL(k_prep, dim3(NB_CONV + NB_TQ + NB_TO + NB_SC), dim3(256), 0, stream,
                       x, Wqkv, Wout, xbf, wqkvT, woutT, tab);
    hipLaunchKernelGGL(k_gemm_qkv, dim3((TN / 128) * (BL / 128)), dim3(256), 0, stream,
                       xbf, wqkvT, bqkv, qb, kb, vt, tab);
    hipLaunchKernelGGL(k_attn, dim3(32 * 16), dim3(512), 0, stream, qb, kb, vt, att);
    hipLaunchKernelGGL(k_gemm_out, dim3((Dm / 128) * (BL / 128)), dim3(256), 0, stream,
                       att, woutT, bout, out);
}

// Round 13
// 122.915 us; speedup vs baseline: 1.1286x; 1.0682x over previous
//
#include <hip/hip_runtime.h>
#include <hip/hip_bf16.h>
#include <math.h>

typedef __bf16 bf16;
typedef __bf16 bf16x8 __attribute__((ext_vector_type(8)));
typedef __bf16 bf16x4 __attribute__((ext_vector_type(4)));
typedef float f32x4 __attribute__((ext_vector_type(4)));
typedef float f32x16 __attribute__((ext_vector_type(16)));

#define DEV __device__ __forceinline__
#define AS1(p) ((const __attribute__((address_space(1))) void*)(p))
#define AS3(p) ((__attribute__((address_space(3))) void*)(p))

// ---------------- problem sizes ----------------
#define Bsz 2
#define Lseq 2048
#define Dm 1024
#define Hh 16
#define HD 64
#define BL (Bsz * Lseq)   // 4096 rows
#define TN (3 * Dm)       // 3072

#define LOG2E 1.44269504088896f

// ---------------- workspace layout (bytes) ----------------
#define OFF_XATT  ((size_t)0)                            // xbf bf16 8.39MB; att aliases after gemm1
#define OFF_WQKVT (OFF_XATT  + (size_t)BL * Dm * 2)      // 6.29MB
#define OFF_WOUTT (OFF_WQKVT + (size_t)TN * Dm * 2)      // 2.10MB
#define OFF_TAB   (OFF_WOUTT + (size_t)Dm * Dm * 2)      // 0.52MB
#define OFF_Q     (OFF_TAB   + (size_t)Lseq * 32 * 8)    // 8.39MB q bf16 [32][2048][64]
#define OFF_K     (OFF_Q     + (size_t)BL * Dm * 2)      // 8.39MB
#define OFF_VT    (OFF_K     + (size_t)BL * Dm * 2)      // 8.39MB vT bf16 [32][64][2048]
// end = 42.5 MB

DEV float exp2_fast(float x) {   // 2^x, single v_exp_f32
    float r;
    asm("v_exp_f32 %0, %1" : "=v"(r) : "v"(x));
    return r;
}
// v_permlane32_swap_b32 a,b: a = {a.lo, b.lo}, b = {a.hi, b.hi}.
// ONLY safe when a and b hold DISTINCT live values (R9 post-mortem).
// R11 post-mortem: no hand-written pk/max3 trees (operand-marshal movs).
DEV void plswap(unsigned& a, unsigned& b) {
    asm("v_permlane32_swap_b32 %0, %1" : "+v"(a), "+v"(b));
}

// ---------------- fused prep: convert + 2 transposes + sincos table --------
// R11 win (-8.8us): one kernel, 4 block-ranges, stages run concurrently.
#define NB_CONV 2048              // (BL*Dm/8)/256
#define NB_TQ   3072              // (TN/32)*(Dm/32)
#define NB_TO   1024              // (Dm/32)*(Dm/32)
#define NB_SC   256               // Lseq*32/256
__global__ __launch_bounds__(256) void k_prep(const float* __restrict__ x,
                                              const float* __restrict__ Wqkv,
                                              const float* __restrict__ Wout,
                                              bf16* __restrict__ xbf,
                                              bf16* __restrict__ wqkvT,
                                              bf16* __restrict__ woutT,
                                              float2* __restrict__ tab) {
    const int bb = blockIdx.x;
    const int tid = threadIdx.x;
    if (bb < NB_CONV) {
        int i = bb * 256 + tid;
        const float4* in4 = (const float4*)x;
        float4 a = in4[i * 2], b = in4[i * 2 + 1];
        bf16x8 o;
        o[0] = (bf16)a.x; o[1] = (bf16)a.y; o[2] = (bf16)a.z; o[3] = (bf16)a.w;
        o[4] = (bf16)b.x; o[5] = (bf16)b.y; o[6] = (bf16)b.z; o[7] = (bf16)b.w;
        ((bf16x8*)xbf)[i] = o;
    } else if (bb < NB_CONV + NB_TQ + NB_TO) {
        const bool isQ = bb < NB_CONV + NB_TQ;
        const int lb = isQ ? bb - NB_CONV : bb - (NB_CONV + NB_TQ);
        const int nx = isQ ? (TN / 32) : (Dm / 32);
        const int C = isQ ? TN : Dm;           // R = Dm for both
        const float* in = isQ ? Wqkv : Wout;
        bf16* out = isQ ? wqkvT : woutT;
        __shared__ float t[32][33];
        const int bx = (lb % nx) * 32, by = (lb / nx) * 32;
        const int tx = tid & 31, ty = tid >> 5;
#pragma unroll
        for (int i = 0; i < 32; i += 8)
            t[ty + i][tx] = in[(size_t)(by + ty + i) * C + bx + tx];
        __syncthreads();
#pragma unroll
        for (int i = 0; i < 32; i += 8)
            out[(size_t)(bx + ty + i) * Dm + by + tx] = (bf16)t[tx][ty + i];
    } else {
        int idx = (bb - (NB_CONV + NB_TQ + NB_TO)) * 256 + tid;
        int pos = idx >> 5, tt = idx & 31;
        float theta = powf(10000.0f, -(float)tt * (1.0f / 32.0f));
        float f = (float)pos * theta;
        tab[idx] = make_float2(sinf(f), cosf(f));
    }
}

DEV f32x4 mfma16(bf16x8 a, bf16x8 b, f32x4 c) {
    return __builtin_amdgcn_mfma_f32_16x16x32_bf16(a, b, c, 0, 0, 0);
}

// ------------- R13: 256x256 QKV GEMM, 8 waves, dbuf 128KB dynamic LDS ------
// One barrier per K-step (attention-proven schedule): issue async stage(t+1)
// -> 64-MFMA compute(t) -> __syncthreads (drains vmcnt+lgkm, protects reuse).
// T2 swizzle identical to the 128^2 kernel (rule #21 both-sides). T5 setprio.
// Fused RoPE/split/Vt epilogue: per-wave 128x64 output = one head's columns;
// 8 slabs of 16 rows through per-wave LDS (rule #20: all acc indices static).
__global__ __launch_bounds__(512, 2) void k_gemm_qkv256(
        const bf16* __restrict__ A, const bf16* __restrict__ BT,
        const float* __restrict__ bias,
        bf16* __restrict__ qo, bf16* __restrict__ ko, bf16* __restrict__ vt,
        const float2* __restrict__ tab) {
    extern __shared__ char dynlds[];   // 131072 B: buf[2] x (A 32KB | B 32KB)
    const int tid = threadIdx.x;
    const int wid = tid >> 6, lane = tid & 63;
    const int lg = lane >> 4, lr = lane & 15;
    const int wr = wid >> 2, wc = wid & 3;     // wave = (wr 0..1) x (wc 0..3)
    // XCD swizzle, 192 blocks, 24/XCD (bijective since 192%8==0)
    const int id = blockIdx.x;
    const int id2 = (id & 7) * 24 + (id >> 3);
    const int n0 = (id2 % 12) * 256;
    const int m0 = (id2 / 12) * 256;
    const char* Ab = (const char*)A;
    const char* Bb = (const char*)BT;
    const size_t Kb = (size_t)Dm * 2;

    f32x4 acc[8][4] = {};

    const int rowL = lane >> 3;
    const int j16 = ((lane & 7) ^ rowL) * 16;  // pre-swizzled source chunk

    // stage one 256x64 A-tile + B-tile into buf (8 global_load_lds / thread)
    auto STAGE = [&](char* buf, int kt) {
        char* Al = buf;
        char* Bl = buf + 32768;
#pragma unroll
        for (int c = 0; c < 4; ++c) {
            const int g = wid * 4 + c;         // 8-row group 0..31
            const int row = g * 8 + rowL;
            __builtin_amdgcn_global_load_lds(
                AS1(Ab + (size_t)(m0 + row) * Kb + kt * 128 + j16),
                AS3(Al + g * 1024), 16, 0, 0);
            __builtin_amdgcn_global_load_lds(
                AS1(Bb + (size_t)(n0 + row) * Kb + kt * 128 + j16),
                AS3(Bl + g * 1024), 16, 0, 0);
        }
    };
    auto COMPUTE = [&](const char* buf) {
        const char* Al = buf + wr * 16384;         // this wave's 128-row half
        const char* Bl = buf + 32768 + wc * 8192;  // this wave's 64-row span
        __builtin_amdgcn_s_setprio(1);
#pragma unroll
        for (int kf = 0; kf < 2; ++kf) {
            bf16x8 af[8], bfr[4];
#pragma unroll
            for (int i = 0; i < 8; ++i) {
                const int ra = i * 16 + lr;
                af[i] = *(const bf16x8*)(Al + ra * 128 + ((kf * 64 + lg * 16) ^ ((ra & 7) << 4)));
            }
#pragma unroll
            for (int j = 0; j < 4; ++j) {
                const int rb = j * 16 + lr;
                bfr[j] = *(const bf16x8*)(Bl + rb * 128 + ((kf * 64 + lg * 16) ^ ((rb & 7) << 4)));
            }
#pragma unroll
            for (int i = 0; i < 8; ++i)
#pragma unroll
                for (int j = 0; j < 4; ++j)
                    acc[i][j] = mfma16(af[i], bfr[j], acc[i][j]);
        }
        __builtin_amdgcn_s_setprio(0);
    };

    STAGE(dynlds, 0);
    __syncthreads();
#pragma unroll 1
    for (int t = 0; t < 16; ++t) {
        char* cur = dynlds + (size_t)(t & 1) * 65536;
        if (t < 15) STAGE(dynlds + (size_t)((t & 1) ^ 1) * 65536, t + 1);
        COMPUTE(cur);
        __syncthreads();
    }

    // ---- fused epilogue: RoPE q (scaled 1/8*log2e), RoPE k, transposed vT --
    const int ph = n0 >> 10;                   // 0=q 1=k 2=v (block-uniform)
    const int c0 = n0 + wc * 64;               // head-aligned 64-col base
    const int h = (c0 & 1023) >> 6;
    const int lrow0 = m0 + wr * 128;
    const int b = lrow0 >> 11;
    const int bh = b * 16 + h;
    const int lbase = lrow0 & 2047;
    float bv[4];
#pragma unroll
    for (int j = 0; j < 4; ++j) bv[j] = bias[c0 + j * 16 + lr];
    float* Lw = (float*)(dynlds + wid * 4096);   // per-wave 16x64 fp32 slab

#pragma unroll   // FULL unroll: compile-time acc indices (rule #20)
    for (int i = 0; i < 8; ++i) {
#pragma unroll
        for (int j = 0; j < 4; ++j)
#pragma unroll
            for (int r = 0; r < 4; ++r)
                Lw[(lg * 4 + r) * 64 + j * 16 + lr] = acc[i][j][r] + bv[j];
        __syncthreads();
        if (ph < 2) {
            const float scale = (ph == 0) ? 0.125f * LOG2E : 1.0f;
            bf16* dst = (ph == 0 ? qo : ko) + (size_t)bh * Lseq * 64;
#pragma unroll
            for (int j = 0; j < 4; ++j)
#pragma unroll
                for (int r = 0; r < 4; ++r) {
                    int rl = lg * 4 + r;
                    int d = j * 16 + lr;
                    int l = lbase + i * 16 + rl;
                    float v = Lw[rl * 64 + d];
                    int dp = (d < 32) ? (2 * d + 1) : (2 * d - 64);
                    float p = Lw[rl * 64 + dp];
                    float2 f = tab[l * 32 + (d & 31)];
                    float val = ((d < 32) ? (v - p) * f.x : (v + p) * f.y) * scale;
                    dst[(size_t)l * 64 + d] = (bf16)val;
                }
        } else {
            int d = lane;
            int lb = lbase + i * 16;
            bf16x8 o1, o2;
#pragma unroll
            for (int rw = 0; rw < 8; ++rw) {
                o1[rw] = (bf16)Lw[rw * 64 + d];
                o2[rw] = (bf16)Lw[(rw + 8) * 64 + d];
            }
            bf16* dst = vt + ((size_t)bh * 64 + d) * Lseq + lb;
            *(bf16x8*)dst = o1;
            *(bf16x8*)(dst + 8) = o2;
        }
        __syncthreads();
    }
}

// ---------------- bf16 GEMM, 128x128 tile, BK=64 (output projection) -------
// global_load_lds staging (rule #21); full-unrolled epilogue (rule #20);
// 1D grid + XCD-chunk swizzle (T1, R8: -4.4us).
__global__ __launch_bounds__(256) void k_gemm_out(const bf16* __restrict__ A,
                                                  const bf16* __restrict__ BT,
                                                  const float* __restrict__ bias,
                                                  float* __restrict__ C) {
    __shared__ uint4 smem4[2048];   // 32KB: A tile 16KB + B tile 16KB
    char* Al = (char*)smem4;
    char* Bl = (char*)smem4 + 16384;
    const int tid = threadIdx.x;
    const int w = tid >> 6, lane = tid & 63, lg = lane >> 4, lr = lane & 15;
    const int id = blockIdx.x;
    const int id2 = (id & 7) * 32 + (id >> 3);    // 256 blocks, 32/XCD
    const int n0 = (id2 & 7) * 128;               // Dm/128 = 8
    const int m0 = (id2 >> 3) * 128;
    const int wm = (w >> 1) * 64, wn = (w & 1) * 64;
    const char* Ab = (const char*)A;
    const char* Bb = (const char*)BT;
    const size_t Kb = (size_t)Dm * 2;

    f32x4 acc[4][4] = {};

    const int rowL = lane >> 3;
    const int j16 = ((lane & 7) ^ rowL) * 16;

    for (int kt = 0; kt < Dm; kt += 64) {
#pragma unroll
        for (int c = 0; c < 4; ++c) {
            const int R0 = (w * 4 + c) * 8;
            const int row = R0 + rowL;
            __builtin_amdgcn_global_load_lds(AS1(Ab + (size_t)(m0 + row) * Kb + kt * 2 + j16),
                                             AS3(Al + R0 * 128), 16, 0, 0);
            __builtin_amdgcn_global_load_lds(AS1(Bb + (size_t)(n0 + row) * Kb + kt * 2 + j16),
                                             AS3(Bl + R0 * 128), 16, 0, 0);
        }
        __syncthreads();
#pragma unroll
        for (int kf = 0; kf < 2; ++kf) {
            bf16x8 af[4], bfr[4];
#pragma unroll
            for (int i = 0; i < 4; ++i) {
                int ra = wm + i * 16 + lr;
                af[i] = *(const bf16x8*)(Al + ra * 128 + ((kf * 64 + lg * 16) ^ ((ra & 7) << 4)));
                int rb = wn + i * 16 + lr;
                bfr[i] = *(const bf16x8*)(Bl + rb * 128 + ((kf * 64 + lg * 16) ^ ((rb & 7) << 4)));
            }
#pragma unroll
            for (int i = 0; i < 4; ++i)
#pragma unroll
                for (int j = 0; j < 4; ++j)
                    acc[i][j] = mfma16(af[i], bfr[j], acc[i][j]);
        }
        __syncthreads();
    }

#pragma unroll
    for (int i = 0; i < 4; ++i) {
        int row = m0 + wm + i * 16 + lg * 4;
#pragma unroll
        for (int j = 0; j < 4; ++j) {
            int col = n0 + wn + j * 16 + lr;
            float bv = bias[col];
#pragma unroll
            for (int r = 0; r < 4; ++r)
                C[(size_t)(row + r) * Dm + col] = acc[i][j][r] + bv;
        }
    }
}

// ---------------- stage 3: flash attention (swapped-operand, 32x32x16) ------
// R12 body verbatim (57.7us known-good).
DEV f32x16 mfma32(bf16x8 a, bf16x8 b, f32x16 c) {
    return __builtin_amdgcn_mfma_f32_32x32x16_bf16(a, b, c, 0, 0, 0);
}
DEV unsigned packbf(float lo, float hi) {
    unsigned short a = __builtin_bit_cast(unsigned short, (bf16)lo);
    unsigned short b = __builtin_bit_cast(unsigned short, (bf16)hi);
    return (unsigned)a | ((unsigned)b << 16);
}

DEV void stage_k(const char* kb, char* dst, int j0, int qw, int lane) {
#pragma unroll
    for (int c = 0; c < 2; ++c) {
        const int j = qw * 2 + c;              // chunk 0..7 (wave-uniform)
        const int rsw = lane ^ j;              // pre-swizzled source row
        __builtin_amdgcn_global_load_lds(AS1(kb + (size_t)(j0 + rsw) * 128 + j * 16),
                                         AS3(dst + j * 1024), 16, 0, 0);
    }
}
DEV void stage_v(const char* vb, char* dst, int j0, int qw, int lane) {
#pragma unroll
    for (int c = 0; c < 2; ++c) {
        const int j = qw * 2 + c;
        const int rsw = lane ^ j;
        __builtin_amdgcn_global_load_lds(AS1(vb + (size_t)rsw * 4096 + (size_t)j0 * 2 + j * 16),
                                         AS3(dst + j * 1024), 16, 0, 0);
    }
}

__global__ __launch_bounds__(512, 4) void k_attn(const bf16* __restrict__ Q,
                                                 const bf16* __restrict__ Kt,
                                                 const bf16* __restrict__ Vt,
                                                 bf16* __restrict__ Op) {
    __shared__ uint4 smem4[4096];   // 64KB: 2 halves x (2 bufs x [K 8K | V 8K])
    char* base = (char*)smem4;
    const int tid = threadIdx.x;
    const int w = tid >> 6, lane = tid & 63;
    const int qw = w & 3, s = w >> 2;
    const int hi = lane >> 5, l31 = lane & 31;
    const int bid = blockIdx.x;
    const int bh = bid >> 4, qt = bid & 15;
    const int q0 = qt * 128 + qw * 32;
    const char* qb = (const char*)(Q + (size_t)bh * Lseq * 64);
    const char* kb = (const char*)(Kt + (size_t)bh * Lseq * 64);
    const char* vb = (const char*)(Vt + (size_t)bh * 64 * Lseq);
    char* setb = base + s * 32768;             // this half's pipeline
    const int jbase = s * 16;                  // this half's first tile index

    // Q frags (B-operand): elem i = Q[q0+l31][kst*16 + hi*8 + i]
    bf16x8 qf[4];
#pragma unroll
    for (int kst = 0; kst < 4; ++kst)
        qf[kst] = *(const bf16x8*)(qb + (size_t)(q0 + l31) * 128 + kst * 32 + hi * 16);

    f32x16 o0 = {}, o1 = {};
    float m = -1e30f, lsum = 0.f;

    // prologue: stage tile 0 of this half into buf 0
    stage_k(kb, setb, jbase * 64, qw, lane);
    stage_v(vb, setb + 8192, jbase * 64, qw, lane);
    __syncthreads();

    for (int t = 0; t < 16; ++t) {
        const int cur = t & 1;
        const char* Kl = setb + cur * 16384;
        const char* Vl = Kl + 8192;
        char* Kn = setb + (cur ^ 1) * 16384;
        char* Vn = Kn + 8192;

        // async-stage next tile (drains at this iteration's end barrier)
        if (t < 15) {
            stage_k(kb, Kn, (jbase + t + 1) * 64, qw, lane);
            stage_v(vb, Vn, (jbase + t + 1) * 64, qw, lane);
        }

        // S^T = K * Q^T : s0 = j rows 0..31, s1 = 32..63 (col q = l31)
        f32x16 s0 = {}, s1 = {};
        __builtin_amdgcn_s_setprio(1);
#pragma unroll
        for (int kst = 0; kst < 4; ++kst) {
            const int jK = kst * 2 + hi;
            const int x = l31 ^ jK;            // jK<8: flips low 3 bits only
            bf16x8 ka = *(const bf16x8*)(Kl + jK * 1024 + x * 16);
            bf16x8 kc = *(const bf16x8*)(Kl + jK * 1024 + (32 + x) * 16);
            s0 = mfma32(ka, qf[kst], s0);
            s1 = mfma32(kc, qf[kst], s1);
        }
        __builtin_amdgcn_s_setprio(0);

        // lane-local online softmax (exp2 domain) for row q = l31
        float pm = fmaxf(s0[0], s0[1]);
#pragma unroll
        for (int r = 2; r < 16; ++r) pm = fmaxf(pm, s0[r]);
#pragma unroll
        for (int r = 0; r < 16; ++r) pm = fmaxf(pm, s1[r]);
        pm = fmaxf(pm, __shfl_xor(pm, 32));
        if (!__all(pm <= m + 8.0f)) {          // defer-max (T13), log2 units
            float mn = fmaxf(m, pm);
            float sc = exp2_fast(m - mn);
#pragma unroll
            for (int r = 0; r < 16; ++r) { o0[r] *= sc; o1[r] *= sc; }
            lsum *= sc; m = mn;
        }
        float rs = 0.f;
#pragma unroll
        for (int r = 0; r < 16; ++r) { s0[r] = exp2_fast(s0[r] - m); rs += s0[r]; }
#pragma unroll
        for (int r = 0; r < 16; ++r) { s1[r] = exp2_fast(s1[r] - m); rs += s1[r]; }
        rs += __shfl_xor(rs, 32);
        lsum += rs;

        // pack P to bf16 pairs; cross-half exchange = 8 in-place permlane
        // swaps on DISTINCT-valued register pairs (safe; see plswap note)
        unsigned u[16];
#pragma unroll
        for (int t2 = 0; t2 < 8; ++t2) {
            u[t2]     = packbf(s0[2 * t2], s0[2 * t2 + 1]);
            u[8 + t2] = packbf(s1[2 * t2], s1[2 * t2 + 1]);
        }
        bf16x8 pf[2][2];
#pragma unroll
        for (int J = 0; J < 2; ++J)
#pragma unroll
            for (int st = 0; st < 2; ++st) {
                const int t0 = J * 8 + st * 4;
                plswap(u[t0 + 0], u[t0 + 2]);
                plswap(u[t0 + 1], u[t0 + 3]);
                union { unsigned wd[4]; bf16x8 v; } f;
                f.wd[0] = u[t0 + 0];
                f.wd[1] = u[t0 + 1];
                f.wd[2] = u[t0 + 2];
                f.wd[3] = u[t0 + 3];
                pf[J][st] = f.v;
            }

        // O^T += V^T * P^T : o0 = d rows 0..31, o1 = 32..63 (col q = l31)
        __builtin_amdgcn_s_setprio(1);
#pragma unroll
        for (int J = 0; J < 2; ++J)
#pragma unroll
            for (int st = 0; st < 2; ++st) {
                const int jV = J * 4 + st * 2 + hi;
                const int x = l31 ^ jV;
                bf16x8 v0 = *(const bf16x8*)(Vl + jV * 1024 + x * 16);
                bf16x8 v1 = *(const bf16x8*)(Vl + jV * 1024 + (32 + x) * 16);
                o0 = mfma32(v0, pf[J][st], o0);
                o1 = mfma32(v1, pf[J][st], o1);
            }
        __builtin_amdgcn_s_setprio(0);
        __syncthreads();
    }

    // ---- combine the two KV halves (LDS exchange; K/V buffers now dead) ----
    float* ex = (float*)base;                   // per qw-wave region: 2176 floats
    if (s == 1) {
        float* r = ex + qw * 2176;
#pragma unroll
        for (int t = 0; t < 16; ++t) {
            r[t * 64 + lane] = o0[t];
            r[1024 + t * 64 + lane] = o1[t];
        }
        r[2048 + lane] = m;
        r[2112 + lane] = lsum;
    }
    __syncthreads();
    if (s == 0) {
        float* r = ex + qw * 2176;
        const float mb = r[2048 + lane], lb = r[2112 + lane];
        const float M = fmaxf(m, mb);
        const float wa = exp2_fast(m - M), wb = exp2_fast(mb - M);
        const float inv = 1.0f / (wa * lsum + wb * lb);
        const float fa = wa * inv, fb = wb * inv;
        const int b = bh >> 4, h = bh & 15;
        bf16* dst = Op + (size_t)(b * Lseq + q0 + l31) * Dm + h * 64;
        // epilogue layout: lane owns col q = l31; rows d = (r&3)+8*(r>>2)+4*hi
#pragma unroll
        for (int t = 0; t < 4; ++t) {
            bf16x4 p0, p1;
#pragma unroll
            for (int i = 0; i < 4; ++i) {
                p0[i] = (bf16)(o0[4 * t + i] * fa + r[(4 * t + i) * 64 + lane] * fb);
                p1[i] = (bf16)(o1[4 * t + i] * fa + r[1024 + (4 * t + i) * 64 + lane] * fb);
            }
            *(bf16x4*)(dst + 8 * t + 4 * hi) = p0;
            *(bf16x4*)(dst + 32 + 8 * t + 4 * hi) = p1;
        }
    }
}

// ---------------- launch ----------------
extern "C" void kernel_launch(void* const* d_in, const int* in_sizes, int n_in,
                              void* d_out, int out_size, void* d_ws, size_t ws_size,
                              hipStream_t stream) {
    (void)in_sizes; (void)n_in; (void)out_size; (void)ws_size;
    const float* x    = (const float*)d_in[0];
    const float* Wqkv = (const float*)d_in[1];
    const float* bqkv = (const float*)d_in[2];
    const float* Wout = (const float*)d_in[3];
    const float* bout = (const float*)d_in[4];
    float* out = (float*)d_out;
    char* ws = (char*)d_ws;

    bf16* xbf    = (bf16*)(ws + OFF_XATT);
    bf16* att    = (bf16*)(ws + OFF_XATT);   // aliases xbf (dead after gemm_qkv)
    bf16* wqkvT  = (bf16*)(ws + OFF_WQKVT);
    bf16* woutT  = (bf16*)(ws + OFF_WOUTT);
    float2* tab  = (float2*)(ws + OFF_TAB);
    bf16* qb     = (bf16*)(ws + OFF_Q);
    bf16* kb     = (bf16*)(ws + OFF_K);
    bf16* vt     = (bf16*)(ws + OFF_VT);

    // idempotent, non-stream call (legal under graph capture): allow 128KB
    // dynamic LDS for the 256^2 QKV GEMM.
    (void)hipFuncSetAttribute((const void*)k_gemm_qkv256,
                              hipFuncAttributeMaxDynamicSharedMemorySize, 131072);

    hipLaunchKernelGGL(k_prep, dim3(NB_CONV + NB_TQ + NB_TO + NB_SC), dim3(256), 0, stream,
                       x, Wqkv, Wout, xbf, wqkvT, woutT, tab);
    hipLaunchKernelGGL(k_gemm_qkv256, dim3(192), dim3(512), 131072, stream,
                       xbf, wqkvT, bqkv, qb, kb, vt, tab);
    hipLaunchKernelGGL(k_attn, dim3(32 * 16), dim3(512), 0, stream, qb, kb, vt, att);
    hipLaunchKernelGGL(k_gemm_out, dim3((Dm / 128) * (BL / 128)), dim3(256), 0, stream,
                       att, woutT, bout, out);
}